// Round 4
// baseline (42916.873 us; speedup 1.0000x reference)
//
#include <hip/hip_runtime.h>
#include <math.h>

typedef short  s16x8 __attribute__((ext_vector_type(8)));
typedef float  f32x4 __attribute__((ext_vector_type(4)));
typedef unsigned short u16;

#define MFMA16(a, b, c) __builtin_amdgcn_mfma_f32_16x16x32_bf16((a), (b), (c), 0, 0, 0)

#define BB 128
#define SS 512
#define HH 512
#define VV 30
#define TT 64

__device__ __forceinline__ float b2f(u16 v) {
  union { unsigned int u; float f; } c; c.u = ((unsigned int)v) << 16; return c.f;
}
__device__ __forceinline__ u16 f2b(float f) {
  union { float f; unsigned int u; } c; c.f = f;
  unsigned int r = (c.u + 0x7FFFu + ((c.u >> 16) & 1u)) >> 16;
  return (u16)r;
}
__device__ __forceinline__ float sigm(float x) { return 1.f / (1.f + expf(-x)); }
__device__ __forceinline__ s16x8 ldf(const u16* p) { return *(const s16x8*)p; }

// Device-scope sense-reversing grid barrier (all blocks co-resident by
// construction: grid <= 128 blocks of 256 thr on 256 CUs).
__device__ __forceinline__ void gbar(int* cnt, int* gen, int nb) {
  __syncthreads();
  if (threadIdx.x == 0) {
    __threadfence();
    int g = __hip_atomic_load(gen, __ATOMIC_RELAXED, __HIP_MEMORY_SCOPE_AGENT);
    int a = __hip_atomic_fetch_add(cnt, 1, __ATOMIC_ACQ_REL, __HIP_MEMORY_SCOPE_AGENT);
    if (a == nb - 1) {
      __hip_atomic_store(cnt, 0, __ATOMIC_RELAXED, __HIP_MEMORY_SCOPE_AGENT);
      __hip_atomic_fetch_add(gen, 1, __ATOMIC_ACQ_REL, __HIP_MEMORY_SCOPE_AGENT);
    } else {
      while (__hip_atomic_load(gen, __ATOMIC_ACQUIRE, __HIP_MEMORY_SCOPE_AGENT) == g)
        __builtin_amdgcn_s_sleep(8);
    }
    __threadfence();
  }
  __syncthreads();
}

// Split-f32 format: per logical row of K=512, u16 row of 1024: [hi x512 | lo x512].
// hi = bf16(v), lo = bf16(v - hi). GEMM does hi*hi + hi*lo + lo*hi (Markidis).

// ---- dual-input GRU cell body (layer-1 / decoder), 64 virtual blocks ----
__device__ __forceinline__ void gru_dual(
    int bx,
    const u16* __restrict__ A1s, const int* __restrict__ gather,
    const u16* __restrict__ A2s,
    const u16* __restrict__ Wihs, const u16* __restrict__ Whhs,
    const float* __restrict__ bih, const float* __restrict__ bhh,
    float* __restrict__ hf, u16* __restrict__ hs_new,
    u16* __restrict__ oe, size_t oe_mstride)
{
  const int tid  = threadIdx.x;
  const int wave = tid >> 6, lane = tid & 63;
  const int lrow = lane & 15, lq = lane >> 4;
  const int j0 = (bx >> 1) * 16;
  const int m0 = (bx & 1) * 64 + wave * 16;

  const u16* a1p;
  if (gather) a1p = A1s + (size_t)gather[m0 + lrow] * 1024 + lq * 8;
  else        a1p = A1s + (size_t)(m0 + lrow) * 1024 + lq * 8;
  const u16* a2p = A2s + (size_t)(m0 + lrow) * 1024 + lq * 8;

  const u16* bp[6];
#pragma unroll
  for (int t = 0; t < 6; ++t) {
    int g = (t < 3) ? t : t - 3;
    const u16* W = (t < 3) ? Wihs : Whhs;
    bp[t] = W + (size_t)(g * HH + j0 + lrow) * 1024 + lq * 8;
  }

  f32x4 acc[6];
#pragma unroll
  for (int t = 0; t < 6; ++t) acc[t] = (f32x4){0.f, 0.f, 0.f, 0.f};

  for (int ks = 0; ks < HH; ks += 32) {
    s16x8 a1h = ldf(a1p), a1l = ldf(a1p + 512); a1p += 32;
    s16x8 a2h = ldf(a2p), a2l = ldf(a2p + 512); a2p += 32;
#pragma unroll
    for (int t = 0; t < 6; ++t) {
      s16x8 bh = ldf(bp[t]), bl = ldf(bp[t] + 512); bp[t] += 32;
      s16x8 ah = (t < 3) ? a1h : a2h;
      s16x8 al = (t < 3) ? a1l : a2l;
      acc[t] = MFMA16(ah, bh, acc[t]);
      acc[t] = MFMA16(ah, bl, acc[t]);
      acc[t] = MFMA16(al, bh, acc[t]);
    }
  }

  const int c = j0 + lrow;
  const float bir = bih[c], biz = bih[HH + c], bin = bih[2 * HH + c];
  const float bhr = bhh[c], bhz = bhh[HH + c], bhn = bhh[2 * HH + c];
#pragma unroll
  for (int r = 0; r < 4; ++r) {
    int m = m0 + lq * 4 + r;
    float ir = acc[0][r] + bir, iz = acc[1][r] + biz, inn = acc[2][r] + bin;
    float hr = acc[3][r] + bhr, hz = acc[4][r] + bhz, hn = acc[5][r] + bhn;
    float rr = sigm(ir + hr);
    float zz = sigm(iz + hz);
    float nn = tanhf(inn + rr * hn);
    float hp = hf[(size_t)m * HH + c];
    float hv = (1.f - zz) * nn + zz * hp;
    hf[(size_t)m * HH + c] = hv;
    u16 hi = f2b(hv);
    hs_new[(size_t)m * 1024 + c]       = hi;
    hs_new[(size_t)m * 1024 + 512 + c] = f2b(hv - b2f(hi));
    if (oe) oe[(size_t)m * oe_mstride + c] = hi;
  }
}

// ---- encoder layer-0 body, 32 virtual blocks ----
__device__ __forceinline__ void gru_l0(
    int bx, int p,
    const float* __restrict__ x, const float* __restrict__ Wih0,
    const u16* __restrict__ Whh0s,
    const float* __restrict__ bih0, const float* __restrict__ bhh0,
    const u16* __restrict__ As,
    float* __restrict__ af, u16* __restrict__ as_new)
{
  const int tid  = threadIdx.x;
  const int wave = tid >> 6, lane = tid & 63;
  const int lrow = lane & 15, lq = lane >> 4;
  const int j0 = bx * 16;
  const int mw = wave * 32;

  const u16* ap0 = As + (size_t)(mw + lrow) * 1024 + lq * 8;
  const u16* ap1 = As + (size_t)(mw + 16 + lrow) * 1024 + lq * 8;
  const u16* bp[3];
#pragma unroll
  for (int t = 0; t < 3; ++t)
    bp[t] = Whh0s + (size_t)(t * HH + j0 + lrow) * 1024 + lq * 8;

  f32x4 acc[2][3];
#pragma unroll
  for (int i = 0; i < 2; ++i)
#pragma unroll
    for (int t = 0; t < 3; ++t) acc[i][t] = (f32x4){0.f, 0.f, 0.f, 0.f};

  for (int ks = 0; ks < HH; ks += 32) {
    s16x8 a0h = ldf(ap0), a0l = ldf(ap0 + 512); ap0 += 32;
    s16x8 a1h = ldf(ap1), a1l = ldf(ap1 + 512); ap1 += 32;
#pragma unroll
    for (int t = 0; t < 3; ++t) {
      s16x8 bh = ldf(bp[t]), bl = ldf(bp[t] + 512); bp[t] += 32;
      acc[0][t] = MFMA16(a0h, bh, acc[0][t]);
      acc[0][t] = MFMA16(a0h, bl, acc[0][t]);
      acc[0][t] = MFMA16(a0l, bh, acc[0][t]);
      acc[1][t] = MFMA16(a1h, bh, acc[1][t]);
      acc[1][t] = MFMA16(a1h, bl, acc[1][t]);
      acc[1][t] = MFMA16(a1l, bh, acc[1][t]);
    }
  }

  const int c = j0 + lrow;
  const float bir = bih0[c], biz = bih0[HH + c], bin = bih0[2 * HH + c];
  const float bhr = bhh0[c], bhz = bhh0[HH + c], bhn = bhh0[2 * HH + c];
  const float wr0 = Wih0[(size_t)c * 2],            wr1 = Wih0[(size_t)c * 2 + 1];
  const float wz0 = Wih0[(size_t)(HH + c) * 2],     wz1 = Wih0[(size_t)(HH + c) * 2 + 1];
  const float wn0 = Wih0[(size_t)(2 * HH + c) * 2], wn1 = Wih0[(size_t)(2 * HH + c) * 2 + 1];
#pragma unroll
  for (int tm = 0; tm < 2; ++tm) {
#pragma unroll
    for (int r = 0; r < 4; ++r) {
      int m = mw + tm * 16 + lq * 4 + r;
      float x0 = x[((size_t)m * SS + p) * 2];
      float x1 = x[((size_t)m * SS + p) * 2 + 1];
      float ir  = bir + x0 * wr0 + x1 * wr1;
      float iz  = biz + x0 * wz0 + x1 * wz1;
      float inn = bin + x0 * wn0 + x1 * wn1;
      float hr = acc[tm][0][r] + bhr, hz = acc[tm][1][r] + bhz, hn = acc[tm][2][r] + bhn;
      float rr = sigm(ir + hr);
      float zz = sigm(iz + hz);
      float nn = tanhf(inn + rr * hn);
      float hp = af[(size_t)m * HH + c];
      float hv = (1.f - zz) * nn + zz * hp;
      af[(size_t)m * HH + c] = hv;
      u16 hi = f2b(hv);
      as_new[(size_t)m * 1024 + c]       = hi;
      as_new[(size_t)m * 1024 + 512 + c] = f2b(hv - b2f(hi));
    }
  }
}

// ===== persistent encoder: all 513 phases, 96 blocks, grid barrier =====
__global__ __launch_bounds__(256) void enc_persist(
    const float* __restrict__ x, const float* __restrict__ Wih0,
    const u16* __restrict__ Whh0s,
    const float* __restrict__ bih0, const float* __restrict__ bhh0,
    const u16* __restrict__ Wih1s, const u16* __restrict__ Whh1s,
    const float* __restrict__ bih1, const float* __restrict__ bhh1,
    u16* A0, u16* A1, float* af, u16* C0, u16* C1, float* cf,
    u16* out_enc, int* bcnt, int* bgen)
{
  const int bx = blockIdx.x;
  u16 *pa = A0, *pan = A1, *pc = C0, *pcn = C1;
  for (int p = 0; p <= SS; ++p) {
    if (bx < 32) {
      if (p < SS) gru_l0(bx, p, x, Wih0, Whh0s, bih0, bhh0, pa, af, pan);
    } else {
      if (p > 0)
        gru_dual(bx - 32, pa, nullptr, pc, Wih1s, Whh1s, bih1, bhh1,
                 cf, pcn, out_enc + (size_t)(p - 1) * HH, (size_t)SS * HH);
    }
    if (p < SS) gbar(bcnt, bgen, 96);
    u16* tp;
    tp = pa; pa = pan; pan = tp;
    tp = pc; pc = pcn; pcn = tp;
  }
}

// ---- sim body: sim[s][b] = dot(out_enc[b,s,:], n1[b,:]) ----
__device__ __forceinline__ void sim_body(
    int vb, const float* __restrict__ n1f, const u16* __restrict__ oe,
    float* __restrict__ simt)
{
  const int b = vb >> 3, sc = vb & 7;
  const int wave = threadIdx.x >> 6, lane = threadIdx.x & 63;
  float xr[8];
  const float* xp = n1f + (size_t)b * HH + lane * 8;
#pragma unroll
  for (int j = 0; j < 8; ++j) xr[j] = xp[j];
  int s0 = sc * 64 + wave * 16;
  for (int i = 0; i < 16; ++i) {
    int s = s0 + i;
    s16x8 ov = *(const s16x8*)(oe + ((size_t)b * SS + s) * HH + lane * 8);
    float acc = 0.f;
#pragma unroll
    for (int j = 0; j < 8; ++j) acc += xr[j] * b2f((u16)ov[j]);
    for (int off = 32; off; off >>= 1) acc += __shfl_down(acc, off);
    if (lane == 0) simt[(size_t)s * BB + b] = acc;
  }
}

// ---- attn body: batch-dim softmax -> attention -> logits -> argmax ----
__device__ __forceinline__ void attn_body(
    int b, int tstep,
    const float* __restrict__ simt, const float* __restrict__ n1f,
    const u16* __restrict__ oe, const float* __restrict__ fcW,
    const float* __restrict__ fcb, float* __restrict__ dout,
    int* __restrict__ tok)
{
  __shared__ float wsm[SS];
  __shared__ float xv[2 * HH];
  __shared__ float lg[32];
  const int t = threadIdx.x;

  for (int s = t; s < SS; s += 256) {
    const float* row = simt + (size_t)s * BB;
    float mx = -1e30f;
    for (int i = 0; i < BB; ++i) mx = fmaxf(mx, row[i]);
    float e = 0.f;
    for (int i = 0; i < BB; ++i) e += expf(row[i] - mx);
    wsm[s] = expf(row[b] - mx) / e;
  }
  xv[t]       = n1f[(size_t)b * HH + t];
  xv[t + 256] = n1f[(size_t)b * HH + t + 256];
  __syncthreads();

  {
    float a0 = 0.f, a1 = 0.f;
    const u16* base = oe + (size_t)b * SS * HH;
    for (int s = 0; s < SS; ++s) {
      float w = wsm[s];
      a0 += w * b2f(base[(size_t)s * HH + t]);
      a1 += w * b2f(base[(size_t)s * HH + t + 256]);
    }
    xv[HH + t]       = a0;
    xv[HH + t + 256] = a1;
  }
  __syncthreads();

  int wave = t >> 6, lane = t & 63;
  for (int v = wave; v < VV; v += 4) {
    const float* wr = fcW + (size_t)v * (2 * HH);
    float acc = 0.f;
#pragma unroll
    for (int i = 0; i < 16; ++i) acc += xv[i * 64 + lane] * wr[i * 64 + lane];
    for (int off = 32; off; off >>= 1) acc += __shfl_down(acc, off);
    if (lane == 0) {
      float lv = acc + fcb[v];
      lg[v] = lv;
      dout[(size_t)b * (TT * VV) + (size_t)tstep * VV + v] = lv;
    }
  }
  __syncthreads();

  if (t == 0) {
    float best = lg[0]; int bi = 0;
    for (int v = 1; v < VV; ++v) if (lg[v] > best) { best = lg[v]; bi = v; }
    tok[b] = bi;
  }
  __syncthreads();
}

// ===== persistent decoder: 64 steps x 4 stages, 128 blocks =====
__global__ __launch_bounds__(256) void dec_persist(
    const u16* __restrict__ EMBs,
    u16* D0c, u16* D0n, u16* D1c, u16* D1n,
    const u16* __restrict__ WdIH0, const u16* __restrict__ WdHH0,
    const float* __restrict__ dbih0, const float* __restrict__ dbhh0,
    const u16* __restrict__ WdIH1, const u16* __restrict__ WdHH1,
    const float* __restrict__ dbih1, const float* __restrict__ dbhh1,
    float* af, float* cf, const u16* __restrict__ oe,
    const float* __restrict__ fcW, const float* __restrict__ fcb,
    float* simt, float* dout, int* tok, int* bcnt, int* bgen)
{
  const int bx = blockIdx.x;
  u16 *d0c = D0c, *d0n = D0n, *d1c = D1c, *d1n = D1n;

  for (int ts = 0; ts < TT; ++ts) {
    if (bx < 64)
      gru_dual(bx, EMBs, tok, d0c, WdIH0, WdHH0, dbih0, dbhh0, af, d0n,
               nullptr, 0);
    gbar(bcnt, bgen, 128);
    u16* tp = d0c; d0c = d0n; d0n = tp;

    if (bx < 64)
      gru_dual(bx, d0c, nullptr, d1c, WdIH1, WdHH1, dbih1, dbhh1, cf, d1n,
               nullptr, 0);
    gbar(bcnt, bgen, 128);
    tp = d1c; d1c = d1n; d1n = tp;

    for (int vb = bx; vb < 1024; vb += 128)
      sim_body(vb, cf, oe, simt);
    gbar(bcnt, bgen, 128);

    attn_body(bx, ts, simt, cf, oe, fcW, fcb, dout, tok);
    if (ts < TT - 1) gbar(bcnt, bgen, 128);
  }

  // hidden output: af = final d0, cf = final d1 (visible via stage barriers).
  float* oh = dout + (size_t)BB * TT * VV;
  for (int i = bx * 256 + threadIdx.x; i < BB * HH; i += 128 * 256) {
    oh[i]           = af[i];
    oh[BB * HH + i] = cf[i];
  }
}

// Split a f32 matrix [rows][512] into [rows][hi x512 | lo x512] u16.
__global__ __launch_bounds__(256) void splitk(
    const float* __restrict__ src, u16* __restrict__ dst, int n)
{
  int i = blockIdx.x * 256 + threadIdx.x;
  if (i >= n) return;
  int r = i >> 9, k = i & 511;
  float v = src[i];
  u16 hi = f2b(v);
  dst[(size_t)r * 1024 + k]       = hi;
  dst[(size_t)r * 1024 + 512 + k] = f2b(v - b2f(hi));
}

__global__ __launch_bounds__(256) void initk(
    float* af, float* cf, u16* b0, u16* b1, u16* b2, u16* b3, int* tok,
    int* bars)
{
  int i = blockIdx.x * 256 + threadIdx.x;   // 131072 threads
  b0[i] = 0; b1[i] = 0; b2[i] = 0; b3[i] = 0;
  if (i < BB * HH) { af[i] = 0.f; cf[i] = 0.f; }
  if (i < BB) tok[i] = 0;
  if (i < 2) bars[i] = 0;
}

extern "C" void kernel_launch(void* const* d_in, const int* in_sizes, int n_in,
                              void* d_out, int out_size, void* d_ws, size_t ws_size,
                              hipStream_t stream) {
  const float* x     = (const float*)d_in[0];
  const float* emb   = (const float*)d_in[1];
  const float* eWih0 = (const float*)d_in[2];
  const float* eWhh0 = (const float*)d_in[3];
  const float* ebih0 = (const float*)d_in[4];
  const float* ebhh0 = (const float*)d_in[5];
  const float* eWih1 = (const float*)d_in[6];
  const float* eWhh1 = (const float*)d_in[7];
  const float* ebih1 = (const float*)d_in[8];
  const float* ebhh1 = (const float*)d_in[9];
  const float* dWih0 = (const float*)d_in[10];
  const float* dWhh0 = (const float*)d_in[11];
  const float* dbih0 = (const float*)d_in[12];
  const float* dbhh0 = (const float*)d_in[13];
  const float* dWih1 = (const float*)d_in[14];
  const float* dWhh1 = (const float*)d_in[15];
  const float* dbih1 = (const float*)d_in[16];
  const float* dbhh1 = (const float*)d_in[17];
  const float* fcW   = (const float*)d_in[18];
  const float* fcb   = (const float*)d_in[19];
  float* dout = (float*)d_out;

  char* wsb = (char*)d_ws;
  float* af   = (float*)(wsb + 0);          // 128x512 f32 (a / d0 master, RMW)
  float* cf   = (float*)(wsb + 262144);     // 128x512 f32 (c / d1 master, RMW)
  u16* ABF0   = (u16*)(wsb + 524288);       // split states 128x1024 u16 each
  u16* ABF1   = (u16*)(wsb + 786432);
  u16* CBF0   = (u16*)(wsb + 1048576);
  u16* CBF1   = (u16*)(wsb + 1310720);
  int* tok    = (int*)(wsb + 1572864);
  float* simt = (float*)(wsb + 1573376);    // [S][B] f32, 256 KB
  u16* WeHH0  = (u16*)(wsb + 1835520);      // split weights, 3 MB each
  u16* WeIH1  = (u16*)(wsb + 4981248);
  u16* WeHH1  = (u16*)(wsb + 8126976);
  u16* WdIH0  = (u16*)(wsb + 11272704);
  u16* WdHH0  = (u16*)(wsb + 14418432);
  u16* WdIH1  = (u16*)(wsb + 17564160);
  u16* WdHH1  = (u16*)(wsb + 20709888);
  u16* EMBs   = (u16*)(wsb + 23855616);     // 30x1024 u16
  u16* oe     = (u16*)(wsb + 23917056);     // out_enc bf16 [B][S][H], 64 MiB

  // barrier vars live in the hidden-state tail of d_out; it is only
  // overwritten by dec_persist's final copy, after the last barrier use.
  int* bars = (int*)(dout + (size_t)BB * TT * VV);

  initk<<<512, 256, 0, stream>>>(af, cf, ABF0, ABF1, CBF0, CBF1, tok, bars);

  const int WN = 3 * HH * HH;               // 786432
  splitk<<<(WN + 255) / 256, 256, 0, stream>>>(eWhh0, WeHH0, WN);
  splitk<<<(WN + 255) / 256, 256, 0, stream>>>(eWih1, WeIH1, WN);
  splitk<<<(WN + 255) / 256, 256, 0, stream>>>(eWhh1, WeHH1, WN);
  splitk<<<(WN + 255) / 256, 256, 0, stream>>>(dWih0, WdIH0, WN);
  splitk<<<(WN + 255) / 256, 256, 0, stream>>>(dWhh0, WdHH0, WN);
  splitk<<<(WN + 255) / 256, 256, 0, stream>>>(dWih1, WdIH1, WN);
  splitk<<<(WN + 255) / 256, 256, 0, stream>>>(dWhh1, WdHH1, WN);
  splitk<<<(VV * HH + 255) / 256, 256, 0, stream>>>(emb, EMBs, VV * HH);

  enc_persist<<<96, 256, 0, stream>>>(x, eWih0, WeHH0, ebih0, ebhh0,
                                      WeIH1, WeHH1, ebih1, ebhh1,
                                      ABF0, ABF1, af, CBF0, CBF1, cf,
                                      oe, bars, bars + 1);

  // phase-parity (as round 3): a_511 split in ABF0, c_511 split in CBF1
  dec_persist<<<128, 256, 0, stream>>>(EMBs, ABF0, ABF1, CBF1, CBF0,
                                       WdIH0, WdHH0, dbih0, dbhh0,
                                       WdIH1, WdHH1, dbih1, dbhh1,
                                       af, cf, oe, fcW, fcb,
                                       simt, dout, tok, bars, bars + 1);
}

// Round 5
// 34105.655 us; speedup vs baseline: 1.2584x; 1.2584x over previous
//
#include <hip/hip_runtime.h>
#include <math.h>

typedef short  s16x8 __attribute__((ext_vector_type(8)));
typedef float  f32x4 __attribute__((ext_vector_type(4)));
typedef unsigned short u16;

#define MFMA16(a, b, c) __builtin_amdgcn_mfma_f32_16x16x32_bf16((a), (b), (c), 0, 0, 0)

#define BB 128
#define SS 512
#define HH 512
#define VV 30
#define TT 64

__device__ __forceinline__ float b2f(u16 v) {
  union { unsigned int u; float f; } c; c.u = ((unsigned int)v) << 16; return c.f;
}
__device__ __forceinline__ u16 f2b(float f) {
  union { float f; unsigned int u; } c; c.f = f;
  unsigned int r = (c.u + 0x7FFFu + ((c.u >> 16) & 1u)) >> 16;
  return (u16)r;
}
__device__ __forceinline__ float sigm(float x) { return 1.f / (1.f + expf(-x)); }
__device__ __forceinline__ s16x8 ldf(const u16* p) { return *(const s16x8*)p; }

// ---------------------------------------------------------------------
// Cheap device-scope grid barrier (all blocks co-resident: grid <= 128).
// Monotonic arrival counter; phase is the 1-based barrier index.
//  - arrive:  RELEASE fetch_add (ONE L2 writeback of our dirty lines)
//  - spin:    RELAXED agent loads (sc1: read coherence point, NO invalidate)
//  - depart:  ONE ACQUIRE load (single L2 invalidate so we see remote data)
// Round-4 bug: spinning on ACQUIRE = L2-invalidate storm -> 98% idle.
// ---------------------------------------------------------------------
__device__ __forceinline__ void gbar(int* cnt, int nb, int phase) {
  __syncthreads();
  if (threadIdx.x == 0) {
    __hip_atomic_fetch_add(cnt, 1, __ATOMIC_RELEASE, __HIP_MEMORY_SCOPE_AGENT);
    const int target = phase * nb;
    while (__hip_atomic_load(cnt, __ATOMIC_RELAXED, __HIP_MEMORY_SCOPE_AGENT) < target)
      __builtin_amdgcn_s_sleep(1);
    (void)__hip_atomic_load(cnt, __ATOMIC_ACQUIRE, __HIP_MEMORY_SCOPE_AGENT);
  }
  __syncthreads();
}

// Split-f32 format: per logical row of K=512, u16 row of 1024: [hi x512 | lo x512].
// hi = bf16(v), lo = bf16(v - hi). GEMM does hi*hi + hi*lo + lo*hi (Markidis).

// ---- dual-input GRU cell body (layer-1 / decoder), 64 virtual blocks ----
__device__ __forceinline__ void gru_dual(
    int bx,
    const u16* __restrict__ A1s, const int* __restrict__ gather,
    const u16* __restrict__ A2s,
    const u16* __restrict__ Wihs, const u16* __restrict__ Whhs,
    const float* __restrict__ bih, const float* __restrict__ bhh,
    float* __restrict__ hf, u16* __restrict__ hs_new,
    u16* __restrict__ oe, size_t oe_mstride)
{
  const int tid  = threadIdx.x;
  const int wave = tid >> 6, lane = tid & 63;
  const int lrow = lane & 15, lq = lane >> 4;
  const int j0 = (bx >> 1) * 16;
  const int m0 = (bx & 1) * 64 + wave * 16;

  const u16* a1p;
  if (gather) a1p = A1s + (size_t)gather[m0 + lrow] * 1024 + lq * 8;
  else        a1p = A1s + (size_t)(m0 + lrow) * 1024 + lq * 8;
  const u16* a2p = A2s + (size_t)(m0 + lrow) * 1024 + lq * 8;

  const u16* bp[6];
#pragma unroll
  for (int t = 0; t < 6; ++t) {
    int g = (t < 3) ? t : t - 3;
    const u16* W = (t < 3) ? Wihs : Whhs;
    bp[t] = W + (size_t)(g * HH + j0 + lrow) * 1024 + lq * 8;
  }

  f32x4 acc[6];
#pragma unroll
  for (int t = 0; t < 6; ++t) acc[t] = (f32x4){0.f, 0.f, 0.f, 0.f};

  for (int ks = 0; ks < HH; ks += 32) {
    s16x8 a1h = ldf(a1p), a1l = ldf(a1p + 512); a1p += 32;
    s16x8 a2h = ldf(a2p), a2l = ldf(a2p + 512); a2p += 32;
#pragma unroll
    for (int t = 0; t < 6; ++t) {
      s16x8 bh = ldf(bp[t]), bl = ldf(bp[t] + 512); bp[t] += 32;
      s16x8 ah = (t < 3) ? a1h : a2h;
      s16x8 al = (t < 3) ? a1l : a2l;
      acc[t] = MFMA16(ah, bh, acc[t]);
      acc[t] = MFMA16(ah, bl, acc[t]);
      acc[t] = MFMA16(al, bh, acc[t]);
    }
  }

  const int c = j0 + lrow;
  const float bir = bih[c], biz = bih[HH + c], bin = bih[2 * HH + c];
  const float bhr = bhh[c], bhz = bhh[HH + c], bhn = bhh[2 * HH + c];
#pragma unroll
  for (int r = 0; r < 4; ++r) {
    int m = m0 + lq * 4 + r;
    float ir = acc[0][r] + bir, iz = acc[1][r] + biz, inn = acc[2][r] + bin;
    float hr = acc[3][r] + bhr, hz = acc[4][r] + bhz, hn = acc[5][r] + bhn;
    float rr = sigm(ir + hr);
    float zz = sigm(iz + hz);
    float nn = tanhf(inn + rr * hn);
    float hp = hf[(size_t)m * HH + c];
    float hv = (1.f - zz) * nn + zz * hp;
    hf[(size_t)m * HH + c] = hv;
    u16 hi = f2b(hv);
    hs_new[(size_t)m * 1024 + c]       = hi;
    hs_new[(size_t)m * 1024 + 512 + c] = f2b(hv - b2f(hi));
    if (oe) oe[(size_t)m * oe_mstride + c] = hi;
  }
}

// ---- encoder layer-0 body, 32 virtual blocks ----
__device__ __forceinline__ void gru_l0(
    int bx, int p,
    const float* __restrict__ x, const float* __restrict__ Wih0,
    const u16* __restrict__ Whh0s,
    const float* __restrict__ bih0, const float* __restrict__ bhh0,
    const u16* __restrict__ As,
    float* __restrict__ af, u16* __restrict__ as_new)
{
  const int tid  = threadIdx.x;
  const int wave = tid >> 6, lane = tid & 63;
  const int lrow = lane & 15, lq = lane >> 4;
  const int j0 = bx * 16;
  const int mw = wave * 32;

  const u16* ap0 = As + (size_t)(mw + lrow) * 1024 + lq * 8;
  const u16* ap1 = As + (size_t)(mw + 16 + lrow) * 1024 + lq * 8;
  const u16* bp[3];
#pragma unroll
  for (int t = 0; t < 3; ++t)
    bp[t] = Whh0s + (size_t)(t * HH + j0 + lrow) * 1024 + lq * 8;

  f32x4 acc[2][3];
#pragma unroll
  for (int i = 0; i < 2; ++i)
#pragma unroll
    for (int t = 0; t < 3; ++t) acc[i][t] = (f32x4){0.f, 0.f, 0.f, 0.f};

  for (int ks = 0; ks < HH; ks += 32) {
    s16x8 a0h = ldf(ap0), a0l = ldf(ap0 + 512); ap0 += 32;
    s16x8 a1h = ldf(ap1), a1l = ldf(ap1 + 512); ap1 += 32;
#pragma unroll
    for (int t = 0; t < 3; ++t) {
      s16x8 bh = ldf(bp[t]), bl = ldf(bp[t] + 512); bp[t] += 32;
      acc[0][t] = MFMA16(a0h, bh, acc[0][t]);
      acc[0][t] = MFMA16(a0h, bl, acc[0][t]);
      acc[0][t] = MFMA16(a0l, bh, acc[0][t]);
      acc[1][t] = MFMA16(a1h, bh, acc[1][t]);
      acc[1][t] = MFMA16(a1h, bl, acc[1][t]);
      acc[1][t] = MFMA16(a1l, bh, acc[1][t]);
    }
  }

  const int c = j0 + lrow;
  const float bir = bih0[c], biz = bih0[HH + c], bin = bih0[2 * HH + c];
  const float bhr = bhh0[c], bhz = bhh0[HH + c], bhn = bhh0[2 * HH + c];
  const float wr0 = Wih0[(size_t)c * 2],            wr1 = Wih0[(size_t)c * 2 + 1];
  const float wz0 = Wih0[(size_t)(HH + c) * 2],     wz1 = Wih0[(size_t)(HH + c) * 2 + 1];
  const float wn0 = Wih0[(size_t)(2 * HH + c) * 2], wn1 = Wih0[(size_t)(2 * HH + c) * 2 + 1];
#pragma unroll
  for (int tm = 0; tm < 2; ++tm) {
#pragma unroll
    for (int r = 0; r < 4; ++r) {
      int m = mw + tm * 16 + lq * 4 + r;
      float x0 = x[((size_t)m * SS + p) * 2];
      float x1 = x[((size_t)m * SS + p) * 2 + 1];
      float ir  = bir + x0 * wr0 + x1 * wr1;
      float iz  = biz + x0 * wz0 + x1 * wz1;
      float inn = bin + x0 * wn0 + x1 * wn1;
      float hr = acc[tm][0][r] + bhr, hz = acc[tm][1][r] + bhz, hn = acc[tm][2][r] + bhn;
      float rr = sigm(ir + hr);
      float zz = sigm(iz + hz);
      float nn = tanhf(inn + rr * hn);
      float hp = af[(size_t)m * HH + c];
      float hv = (1.f - zz) * nn + zz * hp;
      af[(size_t)m * HH + c] = hv;
      u16 hi = f2b(hv);
      as_new[(size_t)m * 1024 + c]       = hi;
      as_new[(size_t)m * 1024 + 512 + c] = f2b(hv - b2f(hi));
    }
  }
}

// ===== persistent encoder: all 513 phases, 96 blocks, grid barrier =====
__global__ __launch_bounds__(256) void enc_persist(
    const float* __restrict__ x, const float* __restrict__ Wih0,
    const u16* __restrict__ Whh0s,
    const float* __restrict__ bih0, const float* __restrict__ bhh0,
    const u16* __restrict__ Wih1s, const u16* __restrict__ Whh1s,
    const float* __restrict__ bih1, const float* __restrict__ bhh1,
    u16* A0, u16* A1, float* af, u16* C0, u16* C1, float* cf,
    u16* out_enc, int* bcnt)
{
  const int bx = blockIdx.x;
  u16 *pa = A0, *pan = A1, *pc = C0, *pcn = C1;
  for (int p = 0; p <= SS; ++p) {
    if (bx < 32) {
      if (p < SS) gru_l0(bx, p, x, Wih0, Whh0s, bih0, bhh0, pa, af, pan);
    } else {
      if (p > 0)
        gru_dual(bx - 32, pa, nullptr, pc, Wih1s, Whh1s, bih1, bhh1,
                 cf, pcn, out_enc + (size_t)(p - 1) * HH, (size_t)SS * HH);
    }
    if (p < SS) gbar(bcnt, 96, p + 1);
    u16* tp;
    tp = pa; pa = pan; pan = tp;
    tp = pc; pc = pcn; pcn = tp;
  }
}

// ---- sim body: sim[s][b] = dot(out_enc[b,s,:], n1[b,:]) ----
__device__ __forceinline__ void sim_body(
    int vb, const float* __restrict__ n1f, const u16* __restrict__ oe,
    float* __restrict__ simt)
{
  const int b = vb >> 3, sc = vb & 7;
  const int wave = threadIdx.x >> 6, lane = threadIdx.x & 63;
  float xr[8];
  const float* xp = n1f + (size_t)b * HH + lane * 8;
#pragma unroll
  for (int j = 0; j < 8; ++j) xr[j] = xp[j];
  int s0 = sc * 64 + wave * 16;
  for (int i = 0; i < 16; ++i) {
    int s = s0 + i;
    s16x8 ov = *(const s16x8*)(oe + ((size_t)b * SS + s) * HH + lane * 8);
    float acc = 0.f;
#pragma unroll
    for (int j = 0; j < 8; ++j) acc += xr[j] * b2f((u16)ov[j]);
    for (int off = 32; off; off >>= 1) acc += __shfl_down(acc, off);
    if (lane == 0) simt[(size_t)s * BB + b] = acc;
  }
}

// ---- attn body: batch-dim softmax -> attention -> logits -> argmax ----
__device__ __forceinline__ void attn_body(
    int b, int tstep,
    const float* __restrict__ simt, const float* __restrict__ n1f,
    const u16* __restrict__ oe, const float* __restrict__ fcW,
    const float* __restrict__ fcb, float* __restrict__ dout,
    int* __restrict__ tok)
{
  __shared__ float wsm[SS];
  __shared__ float xv[2 * HH];
  __shared__ float lg[32];
  const int t = threadIdx.x;

  for (int s = t; s < SS; s += 256) {
    const float* row = simt + (size_t)s * BB;
    float mx = -1e30f;
    for (int i = 0; i < BB; ++i) mx = fmaxf(mx, row[i]);
    float e = 0.f;
    for (int i = 0; i < BB; ++i) e += expf(row[i] - mx);
    wsm[s] = expf(row[b] - mx) / e;
  }
  xv[t]       = n1f[(size_t)b * HH + t];
  xv[t + 256] = n1f[(size_t)b * HH + t + 256];
  __syncthreads();

  {
    float a0 = 0.f, a1 = 0.f;
    const u16* base = oe + (size_t)b * SS * HH;
    for (int s = 0; s < SS; ++s) {
      float w = wsm[s];
      a0 += w * b2f(base[(size_t)s * HH + t]);
      a1 += w * b2f(base[(size_t)s * HH + t + 256]);
    }
    xv[HH + t]       = a0;
    xv[HH + t + 256] = a1;
  }
  __syncthreads();

  int wave = t >> 6, lane = t & 63;
  for (int v = wave; v < VV; v += 4) {
    const float* wr = fcW + (size_t)v * (2 * HH);
    float acc = 0.f;
#pragma unroll
    for (int i = 0; i < 16; ++i) acc += xv[i * 64 + lane] * wr[i * 64 + lane];
    for (int off = 32; off; off >>= 1) acc += __shfl_down(acc, off);
    if (lane == 0) {
      float lv = acc + fcb[v];
      lg[v] = lv;
      dout[(size_t)b * (TT * VV) + (size_t)tstep * VV + v] = lv;
    }
  }
  __syncthreads();

  if (t == 0) {
    float best = lg[0]; int bi = 0;
    for (int v = 1; v < VV; ++v) if (lg[v] > best) { best = lg[v]; bi = v; }
    tok[b] = bi;
  }
  __syncthreads();
}

// ===== persistent decoder: 64 steps x 4 stages, 128 blocks =====
__global__ __launch_bounds__(256) void dec_persist(
    const u16* __restrict__ EMBs,
    u16* D0c, u16* D0n, u16* D1c, u16* D1n,
    const u16* __restrict__ WdIH0, const u16* __restrict__ WdHH0,
    const float* __restrict__ dbih0, const float* __restrict__ dbhh0,
    const u16* __restrict__ WdIH1, const u16* __restrict__ WdHH1,
    const float* __restrict__ dbih1, const float* __restrict__ dbhh1,
    float* af, float* cf, const u16* __restrict__ oe,
    const float* __restrict__ fcW, const float* __restrict__ fcb,
    float* simt, float* dout, int* tok, int* bcnt)
{
  const int bx = blockIdx.x;
  u16 *d0c = D0c, *d0n = D0n, *d1c = D1c, *d1n = D1n;
  int bar = 0;

  for (int ts = 0; ts < TT; ++ts) {
    if (bx < 64)
      gru_dual(bx, EMBs, tok, d0c, WdIH0, WdHH0, dbih0, dbhh0, af, d0n,
               nullptr, 0);
    gbar(bcnt, 128, ++bar);
    u16* tp = d0c; d0c = d0n; d0n = tp;

    if (bx < 64)
      gru_dual(bx, d0c, nullptr, d1c, WdIH1, WdHH1, dbih1, dbhh1, cf, d1n,
               nullptr, 0);
    gbar(bcnt, 128, ++bar);
    tp = d1c; d1c = d1n; d1n = tp;

    for (int vb = bx; vb < 1024; vb += 128)
      sim_body(vb, cf, oe, simt);
    gbar(bcnt, 128, ++bar);

    attn_body(bx, ts, simt, cf, oe, fcW, fcb, dout, tok);
    if (ts < TT - 1) gbar(bcnt, 128, ++bar);
  }

  // hidden output: af = final d0, cf = final d1 (visible via stage barriers).
  float* oh = dout + (size_t)BB * TT * VV;
  for (int i = bx * 256 + threadIdx.x; i < BB * HH; i += 128 * 256) {
    oh[i]           = af[i];
    oh[BB * HH + i] = cf[i];
  }
}

// Split a f32 matrix [rows][512] into [rows][hi x512 | lo x512] u16.
__global__ __launch_bounds__(256) void splitk(
    const float* __restrict__ src, u16* __restrict__ dst, int n)
{
  int i = blockIdx.x * 256 + threadIdx.x;
  if (i >= n) return;
  int r = i >> 9, k = i & 511;
  float v = src[i];
  u16 hi = f2b(v);
  dst[(size_t)r * 1024 + k]       = hi;
  dst[(size_t)r * 1024 + 512 + k] = f2b(v - b2f(hi));
}

__global__ __launch_bounds__(256) void initk(
    float* af, float* cf, u16* b0, u16* b1, u16* b2, u16* b3, int* tok,
    int* bars)
{
  int i = blockIdx.x * 256 + threadIdx.x;   // 131072 threads
  b0[i] = 0; b1[i] = 0; b2[i] = 0; b3[i] = 0;
  if (i < BB * HH) { af[i] = 0.f; cf[i] = 0.f; }
  if (i < BB) tok[i] = 0;
  if (i < 2) bars[i] = 0;
}

extern "C" void kernel_launch(void* const* d_in, const int* in_sizes, int n_in,
                              void* d_out, int out_size, void* d_ws, size_t ws_size,
                              hipStream_t stream) {
  const float* x     = (const float*)d_in[0];
  const float* emb   = (const float*)d_in[1];
  const float* eWih0 = (const float*)d_in[2];
  const float* eWhh0 = (const float*)d_in[3];
  const float* ebih0 = (const float*)d_in[4];
  const float* ebhh0 = (const float*)d_in[5];
  const float* eWih1 = (const float*)d_in[6];
  const float* eWhh1 = (const float*)d_in[7];
  const float* ebih1 = (const float*)d_in[8];
  const float* ebhh1 = (const float*)d_in[9];
  const float* dWih0 = (const float*)d_in[10];
  const float* dWhh0 = (const float*)d_in[11];
  const float* dbih0 = (const float*)d_in[12];
  const float* dbhh0 = (const float*)d_in[13];
  const float* dWih1 = (const float*)d_in[14];
  const float* dWhh1 = (const float*)d_in[15];
  const float* dbih1 = (const float*)d_in[16];
  const float* dbhh1 = (const float*)d_in[17];
  const float* fcW   = (const float*)d_in[18];
  const float* fcb   = (const float*)d_in[19];
  float* dout = (float*)d_out;

  char* wsb = (char*)d_ws;
  float* af   = (float*)(wsb + 0);          // 128x512 f32 (a / d0 master, RMW)
  float* cf   = (float*)(wsb + 262144);     // 128x512 f32 (c / d1 master, RMW)
  u16* ABF0   = (u16*)(wsb + 524288);       // split states 128x1024 u16 each
  u16* ABF1   = (u16*)(wsb + 786432);
  u16* CBF0   = (u16*)(wsb + 1048576);
  u16* CBF1   = (u16*)(wsb + 1310720);
  int* tok    = (int*)(wsb + 1572864);
  float* simt = (float*)(wsb + 1573376);    // [S][B] f32, 256 KB
  u16* WeHH0  = (u16*)(wsb + 1835520);      // split weights, 3 MB each
  u16* WeIH1  = (u16*)(wsb + 4981248);
  u16* WeHH1  = (u16*)(wsb + 8126976);
  u16* WdIH0  = (u16*)(wsb + 11272704);
  u16* WdHH0  = (u16*)(wsb + 14418432);
  u16* WdIH1  = (u16*)(wsb + 17564160);
  u16* WdHH1  = (u16*)(wsb + 20709888);
  u16* EMBs   = (u16*)(wsb + 23855616);     // 30x1024 u16
  u16* oe     = (u16*)(wsb + 23917056);     // out_enc bf16 [B][S][H], 64 MiB

  // barrier counters live in the hidden-state tail of d_out; it is only
  // overwritten by dec_persist's final copy, after the last barrier use.
  int* bars = (int*)(dout + (size_t)BB * TT * VV);

  initk<<<512, 256, 0, stream>>>(af, cf, ABF0, ABF1, CBF0, CBF1, tok, bars);

  const int WN = 3 * HH * HH;               // 786432
  splitk<<<(WN + 255) / 256, 256, 0, stream>>>(eWhh0, WeHH0, WN);
  splitk<<<(WN + 255) / 256, 256, 0, stream>>>(eWih1, WeIH1, WN);
  splitk<<<(WN + 255) / 256, 256, 0, stream>>>(eWhh1, WeHH1, WN);
  splitk<<<(WN + 255) / 256, 256, 0, stream>>>(dWih0, WdIH0, WN);
  splitk<<<(WN + 255) / 256, 256, 0, stream>>>(dWhh0, WdHH0, WN);
  splitk<<<(WN + 255) / 256, 256, 0, stream>>>(dWih1, WdIH1, WN);
  splitk<<<(WN + 255) / 256, 256, 0, stream>>>(dWhh1, WdHH1, WN);
  splitk<<<(VV * HH + 255) / 256, 256, 0, stream>>>(emb, EMBs, VV * HH);

  enc_persist<<<96, 256, 0, stream>>>(x, eWih0, WeHH0, ebih0, ebhh0,
                                      WeIH1, WeHH1, ebih1, ebhh1,
                                      ABF0, ABF1, af, CBF0, CBF1, cf,
                                      oe, bars);

  // phase-parity (as round 3): a_511 split in ABF0, c_511 split in CBF1
  dec_persist<<<128, 256, 0, stream>>>(EMBs, ABF0, ABF1, CBF1, CBF0,
                                       WdIH0, WdHH0, dbih0, dbhh0,
                                       WdIH1, WdHH1, dbih1, dbhh1,
                                       af, cf, oe, fcW, fcb,
                                       simt, dout, tok, bars + 1);
}

// Round 8
// 33698.132 us; speedup vs baseline: 1.2736x; 1.0121x over previous
//
#include <hip/hip_runtime.h>
#include <math.h>

typedef short  s16x8 __attribute__((ext_vector_type(8)));
typedef float  f32x4 __attribute__((ext_vector_type(4)));
typedef unsigned short u16;

#define MFMA16(a, b, c) __builtin_amdgcn_mfma_f32_16x16x32_bf16((a), (b), (c), 0, 0, 0)

#define BB 128
#define SS 512
#define HH 512
#define VV 30
#define TT 64

__device__ __forceinline__ float b2f(u16 v) {
  union { unsigned int u; float f; } c; c.u = ((unsigned int)v) << 16; return c.f;
}
__device__ __forceinline__ u16 f2b(float f) {
  union { float f; unsigned int u; } c; c.f = f;
  unsigned int r = (c.u + 0x7FFFu + ((c.u >> 16) & 1u)) >> 16;
  return (u16)r;
}
__device__ __forceinline__ float sigm(float x) { return 1.f / (1.f + expf(-x)); }
__device__ __forceinline__ s16x8 ldf(const u16* p) { return *(const s16x8*)p; }

// ---- device-coherent (sc1) accessors: bypass non-coherent per-XCD L2,
// ---- served at the shared coherence point. Compiler-tracked (normal
// ---- waitcnt insertion), pipeline like plain loads.
__device__ __forceinline__ unsigned long long lda64(const void* p) {
  return __hip_atomic_load((const unsigned long long*)p, __ATOMIC_RELAXED,
                           __HIP_MEMORY_SCOPE_AGENT);
}
__device__ __forceinline__ s16x8 ldc(const u16* p) {   // 16B coherent load
  union { unsigned long long q[2]; s16x8 v; } u;
  u.q[0] = lda64(p);
  u.q[1] = lda64(p + 4);
  return u.v;
}
__device__ __forceinline__ u16 lda16(const u16* p) {
  return __hip_atomic_load(p, __ATOMIC_RELAXED, __HIP_MEMORY_SCOPE_AGENT);
}
__device__ __forceinline__ void sta16(u16* p, u16 v) {
  __hip_atomic_store(p, v, __ATOMIC_RELAXED, __HIP_MEMORY_SCOPE_AGENT);
}
__device__ __forceinline__ float lda32f(const float* p) {
  return __hip_atomic_load(p, __ATOMIC_RELAXED, __HIP_MEMORY_SCOPE_AGENT);
}
__device__ __forceinline__ void sta32f(float* p, float v) {
  __hip_atomic_store(p, v, __ATOMIC_RELAXED, __HIP_MEMORY_SCOPE_AGENT);
}
__device__ __forceinline__ int lda32i(const int* p) {
  return __hip_atomic_load(p, __ATOMIC_RELAXED, __HIP_MEMORY_SCOPE_AGENT);
}
__device__ __forceinline__ void sta32i(int* p, int v) {
  __hip_atomic_store(p, v, __ATOMIC_RELAXED, __HIP_MEMORY_SCOPE_AGENT);
}

// ---------------------------------------------------------------------
// Fence-free grid barrier. All cross-block data moves via sc1 accesses
// (write-through to the coherence point), so the barrier needs NO
// acquire/release: __syncthreads drains each wave's vmcnt (compiler emits
// s_waitcnt vmcnt(0) before s_barrier), then a relaxed arrival + relaxed
// spin. No buffer_inv / buffer_wbl2, so weights stay L2-resident.
// Round-4 bug: acquire spin = L2-invalidate storm. Round-5 residual:
// one acquire+release per block per barrier still evicted L2 every phase.
// ---------------------------------------------------------------------
__device__ __forceinline__ void gbar(int* cnt, int nb, int phase) {
  __syncthreads();
  if (threadIdx.x == 0) {
    __hip_atomic_fetch_add(cnt, 1, __ATOMIC_RELAXED, __HIP_MEMORY_SCOPE_AGENT);
    const int target = phase * nb;
    while (__hip_atomic_load(cnt, __ATOMIC_RELAXED, __HIP_MEMORY_SCOPE_AGENT) < target)
      __builtin_amdgcn_s_sleep(4);
  }
  __syncthreads();
}

// Split-f32: row of 1024 u16 = [hi x512 | lo x512]; GEMM = hi*hi+hi*lo+lo*hi.

// ---- dual-input GRU cell body (layer-1 / decoder), 64 virtual blocks ----
__device__ __forceinline__ void gru_dual(
    int bx,
    const u16* __restrict__ A1s, const int* __restrict__ gather,
    const u16* __restrict__ A2s,
    const u16* __restrict__ Wihs, const u16* __restrict__ Whhs,
    const float* __restrict__ bih, const float* __restrict__ bhh,
    float* __restrict__ hf, u16* __restrict__ hs_new,
    u16* __restrict__ oe, size_t oe_mstride, float* __restrict__ ohp)
{
  const int tid  = threadIdx.x;
  const int wave = tid >> 6, lane = tid & 63;
  const int lrow = lane & 15, lq = lane >> 4;
  const int j0 = (bx >> 1) * 16;
  const int m0 = (bx & 1) * 64 + wave * 16;

  const u16* a1p;
  if (gather) a1p = A1s + (size_t)lda32i(gather + m0 + lrow) * 1024 + lq * 8;
  else        a1p = A1s + (size_t)(m0 + lrow) * 1024 + lq * 8;
  const u16* a2p = A2s + (size_t)(m0 + lrow) * 1024 + lq * 8;

  const u16* bp[6];
#pragma unroll
  for (int t = 0; t < 6; ++t) {
    int g = (t < 3) ? t : t - 3;
    const u16* W = (t < 3) ? Wihs : Whhs;
    bp[t] = W + (size_t)(g * HH + j0 + lrow) * 1024 + lq * 8;
  }

  f32x4 acc[6];
#pragma unroll
  for (int t = 0; t < 6; ++t) acc[t] = (f32x4){0.f, 0.f, 0.f, 0.f};

  for (int ks = 0; ks < HH; ks += 32) {
    s16x8 a1h = ldc(a1p), a1l = ldc(a1p + 512); a1p += 32;
    s16x8 a2h = ldc(a2p), a2l = ldc(a2p + 512); a2p += 32;
#pragma unroll
    for (int t = 0; t < 6; ++t) {
      s16x8 bh = ldf(bp[t]), bl = ldf(bp[t] + 512); bp[t] += 32;
      s16x8 ah = (t < 3) ? a1h : a2h;
      s16x8 al = (t < 3) ? a1l : a2l;
      acc[t] = MFMA16(ah, bh, acc[t]);
      acc[t] = MFMA16(ah, bl, acc[t]);
      acc[t] = MFMA16(al, bh, acc[t]);
    }
  }

  const int c = j0 + lrow;
  const float bir = bih[c], biz = bih[HH + c], bin = bih[2 * HH + c];
  const float bhr = bhh[c], bhz = bhh[HH + c], bhn = bhh[2 * HH + c];
#pragma unroll
  for (int r = 0; r < 4; ++r) {
    int m = m0 + lq * 4 + r;
    float ir = acc[0][r] + bir, iz = acc[1][r] + biz, inn = acc[2][r] + bin;
    float hr = acc[3][r] + bhr, hz = acc[4][r] + bhz, hn = acc[5][r] + bhn;
    float rr = sigm(ir + hr);
    float zz = sigm(iz + hz);
    float nn = tanhf(inn + rr * hn);
    float hp = hf[(size_t)m * HH + c];
    float hv = (1.f - zz) * nn + zz * hp;
    hf[(size_t)m * HH + c] = hv;       // block-private across phases: cached
    u16 hi = f2b(hv);
    sta16(hs_new + (size_t)m * 1024 + c, hi);            // cross-block: sc1
    sta16(hs_new + (size_t)m * 1024 + 512 + c, f2b(hv - b2f(hi)));
    if (oe)  oe[(size_t)m * oe_mstride + c] = hi;        // read next kernel
    if (ohp) ohp[(size_t)m * HH + c] = hv;               // final hidden out
  }
}

// ---- encoder layer-0 body, 32 virtual blocks ----
__device__ __forceinline__ void gru_l0(
    int bx, int p,
    const float* __restrict__ x, const float* __restrict__ Wih0,
    const u16* __restrict__ Whh0s,
    const float* __restrict__ bih0, const float* __restrict__ bhh0,
    const u16* __restrict__ As,
    float* __restrict__ af, u16* __restrict__ as_new)
{
  const int tid  = threadIdx.x;
  const int wave = tid >> 6, lane = tid & 63;
  const int lrow = lane & 15, lq = lane >> 4;
  const int j0 = bx * 16;
  const int mw = wave * 32;

  const u16* ap0 = As + (size_t)(mw + lrow) * 1024 + lq * 8;
  const u16* ap1 = As + (size_t)(mw + 16 + lrow) * 1024 + lq * 8;
  const u16* bp[3];
#pragma unroll
  for (int t = 0; t < 3; ++t)
    bp[t] = Whh0s + (size_t)(t * HH + j0 + lrow) * 1024 + lq * 8;

  f32x4 acc[2][3];
#pragma unroll
  for (int i = 0; i < 2; ++i)
#pragma unroll
    for (int t = 0; t < 3; ++t) acc[i][t] = (f32x4){0.f, 0.f, 0.f, 0.f};

  for (int ks = 0; ks < HH; ks += 32) {
    s16x8 a0h = ldc(ap0), a0l = ldc(ap0 + 512); ap0 += 32;
    s16x8 a1h = ldc(ap1), a1l = ldc(ap1 + 512); ap1 += 32;
#pragma unroll
    for (int t = 0; t < 3; ++t) {
      s16x8 bh = ldf(bp[t]), bl = ldf(bp[t] + 512); bp[t] += 32;
      acc[0][t] = MFMA16(a0h, bh, acc[0][t]);
      acc[0][t] = MFMA16(a0h, bl, acc[0][t]);
      acc[0][t] = MFMA16(a0l, bh, acc[0][t]);
      acc[1][t] = MFMA16(a1h, bh, acc[1][t]);
      acc[1][t] = MFMA16(a1h, bl, acc[1][t]);
      acc[1][t] = MFMA16(a1l, bh, acc[1][t]);
    }
  }

  const int c = j0 + lrow;
  const float bir = bih0[c], biz = bih0[HH + c], bin = bih0[2 * HH + c];
  const float bhr = bhh0[c], bhz = bhh0[HH + c], bhn = bhh0[2 * HH + c];
  const float wr0 = Wih0[(size_t)c * 2],            wr1 = Wih0[(size_t)c * 2 + 1];
  const float wz0 = Wih0[(size_t)(HH + c) * 2],     wz1 = Wih0[(size_t)(HH + c) * 2 + 1];
  const float wn0 = Wih0[(size_t)(2 * HH + c) * 2], wn1 = Wih0[(size_t)(2 * HH + c) * 2 + 1];
#pragma unroll
  for (int tm = 0; tm < 2; ++tm) {
#pragma unroll
    for (int r = 0; r < 4; ++r) {
      int m = mw + tm * 16 + lq * 4 + r;
      float x0 = x[((size_t)m * SS + p) * 2];
      float x1 = x[((size_t)m * SS + p) * 2 + 1];
      float ir  = bir + x0 * wr0 + x1 * wr1;
      float iz  = biz + x0 * wz0 + x1 * wz1;
      float inn = bin + x0 * wn0 + x1 * wn1;
      float hr = acc[tm][0][r] + bhr, hz = acc[tm][1][r] + bhz, hn = acc[tm][2][r] + bhn;
      float rr = sigm(ir + hr);
      float zz = sigm(iz + hz);
      float nn = tanhf(inn + rr * hn);
      float hp = af[(size_t)m * HH + c];
      float hv = (1.f - zz) * nn + zz * hp;
      af[(size_t)m * HH + c] = hv;     // block-private: cached
      u16 hi = f2b(hv);
      sta16(as_new + (size_t)m * 1024 + c, hi);          // cross-block: sc1
      sta16(as_new + (size_t)m * 1024 + 512 + c, f2b(hv - b2f(hi)));
    }
  }
}

// ===== persistent encoder: all 513 phases, 96 blocks, grid barrier =====
__global__ __launch_bounds__(256) void enc_persist(
    const float* __restrict__ x, const float* __restrict__ Wih0,
    const u16* __restrict__ Whh0s,
    const float* __restrict__ bih0, const float* __restrict__ bhh0,
    const u16* __restrict__ Wih1s, const u16* __restrict__ Whh1s,
    const float* __restrict__ bih1, const float* __restrict__ bhh1,
    u16* A0, u16* A1, float* af, u16* C0, u16* C1, float* cf,
    u16* out_enc, int* bcnt)
{
  const int bx = blockIdx.x;
  u16 *pa = A0, *pan = A1, *pc = C0, *pcn = C1;
  for (int p = 0; p <= SS; ++p) {
    if (bx < 32) {
      if (p < SS) gru_l0(bx, p, x, Wih0, Whh0s, bih0, bhh0, pa, af, pan);
    } else {
      if (p > 0)
        gru_dual(bx - 32, pa, nullptr, pc, Wih1s, Whh1s, bih1, bhh1,
                 cf, pcn, out_enc + (size_t)(p - 1) * HH, (size_t)SS * HH,
                 nullptr);
    }
    if (p < SS) gbar(bcnt, 96, p + 1);
    u16* tp;
    tp = pa; pa = pan; pan = tp;
    tp = pc; pc = pcn; pcn = tp;
  }
}

// ---- sim body: sim[s][b] = dot(oe[b,s,:], n1[b,:]); n1 from split state ----
__device__ __forceinline__ void sim_body(
    int vb, const u16* __restrict__ n1s, const u16* __restrict__ oe,
    float* __restrict__ simt)
{
  const int b = vb >> 3, sc = vb & 7;
  const int wave = threadIdx.x >> 6, lane = threadIdx.x & 63;
  s16x8 xh = ldc(n1s + (size_t)b * 1024 + lane * 8);
  s16x8 xl = ldc(n1s + (size_t)b * 1024 + 512 + lane * 8);
  float xr[8];
#pragma unroll
  for (int j = 0; j < 8; ++j) xr[j] = b2f((u16)xh[j]) + b2f((u16)xl[j]);
  int s0 = sc * 64 + wave * 16;
  for (int i = 0; i < 16; ++i) {
    int s = s0 + i;
    s16x8 ov = *(const s16x8*)(oe + ((size_t)b * SS + s) * HH + lane * 8);
    float acc = 0.f;
#pragma unroll
    for (int j = 0; j < 8; ++j) acc += xr[j] * b2f((u16)ov[j]);
    for (int off = 32; off; off >>= 1) acc += __shfl_down(acc, off);
    if (lane == 0) sta32f(simt + (size_t)s * BB + b, acc);
  }
}

// ---- per-s batch max/sum pre-pass: one wave per s (128 blocks x 4 waves) ----
__device__ __forceinline__ void smax_body(
    int bx, const float* __restrict__ simt,
    float* __restrict__ smax, float* __restrict__ ssum)
{
  const int wave = threadIdx.x >> 6, lane = threadIdx.x & 63;
  const int s = bx * 4 + wave;
  union { unsigned long long q; float f[2]; } u;
  u.q = lda64(simt + (size_t)s * BB + lane * 2);
  float mx = fmaxf(u.f[0], u.f[1]);
  for (int off = 32; off; off >>= 1) mx = fmaxf(mx, __shfl_down(mx, off));
  mx = __shfl(mx, 0);
  float e = expf(u.f[0] - mx) + expf(u.f[1] - mx);
  for (int off = 32; off; off >>= 1) e += __shfl_down(e, off);
  if (lane == 0) { sta32f(smax + s, mx); sta32f(ssum + s, e); }
}

// ---- attn body: batch-softmax -> attention -> logits -> argmax ----
__device__ __forceinline__ void attn_body(
    int b, int tstep,
    const float* __restrict__ simt, const float* __restrict__ smax,
    const float* __restrict__ ssum, const u16* __restrict__ n1s,
    const u16* __restrict__ oe, const float* __restrict__ fcW,
    const float* __restrict__ fcb, float* __restrict__ dout,
    int* __restrict__ tok)
{
  __shared__ float wsm[SS];
  __shared__ float xv[2 * HH];
  __shared__ float lg[32];
  const int t = threadIdx.x;

  for (int s = t; s < SS; s += 256) {
    float mx = lda32f(smax + s), e = lda32f(ssum + s);
    float rb = lda32f(simt + (size_t)s * BB + b);
    wsm[s] = expf(rb - mx) / e;
  }
  const u16* nb = n1s + (size_t)b * 1024;
  xv[t]       = b2f(lda16(nb + t))       + b2f(lda16(nb + 512 + t));
  xv[t + 256] = b2f(lda16(nb + t + 256)) + b2f(lda16(nb + 768 + t));
  __syncthreads();

  {
    float a0 = 0.f, a1 = 0.f;
    const u16* base = oe + (size_t)b * SS * HH;
    for (int s = 0; s < SS; ++s) {
      float w = wsm[s];
      a0 += w * b2f(base[(size_t)s * HH + t]);
      a1 += w * b2f(base[(size_t)s * HH + t + 256]);
    }
    xv[HH + t]       = a0;
    xv[HH + t + 256] = a1;
  }
  __syncthreads();

  int wave = t >> 6, lane = t & 63;
  for (int v = wave; v < VV; v += 4) {
    const float* wr = fcW + (size_t)v * (2 * HH);
    float acc = 0.f;
#pragma unroll
    for (int i = 0; i < 16; ++i) acc += xv[i * 64 + lane] * wr[i * 64 + lane];
    for (int off = 32; off; off >>= 1) acc += __shfl_down(acc, off);
    if (lane == 0) {
      float lv = acc + fcb[v];
      lg[v] = lv;
      dout[(size_t)b * (TT * VV) + (size_t)tstep * VV + v] = lv;
    }
  }
  __syncthreads();

  if (t == 0) {
    float best = lg[0]; int bi = 0;
    for (int v = 1; v < VV; ++v) if (lg[v] > best) { best = lg[v]; bi = v; }
    sta32i(tok + b, bi);
  }
  __syncthreads();
}

// ===== persistent decoder: 64 steps x 5 stages, 128 blocks =====
__global__ __launch_bounds__(256) void dec_persist(
    const u16* __restrict__ EMBs,
    u16* D0c, u16* D0n, u16* D1c, u16* D1n,
    const u16* __restrict__ WdIH0, const u16* __restrict__ WdHH0,
    const float* __restrict__ dbih0, const float* __restrict__ dbhh0,
    const u16* __restrict__ WdIH1, const u16* __restrict__ WdHH1,
    const float* __restrict__ dbih1, const float* __restrict__ dbhh1,
    float* af, float* cf, const u16* __restrict__ oe,
    const float* __restrict__ fcW, const float* __restrict__ fcb,
    float* simt, float* smax, float* ssum,
    float* dout, int* tok, int* bcnt)
{
  const int bx = blockIdx.x;
  u16 *d0c = D0c, *d0n = D0n, *d1c = D1c, *d1n = D1n;
  float* oh = dout + (size_t)BB * TT * VV;
  int bar = 0;

  for (int ts = 0; ts < TT; ++ts) {
    const bool last = (ts == TT - 1);
    if (bx < 64)
      gru_dual(bx, EMBs, tok, d0c, WdIH0, WdHH0, dbih0, dbhh0, af, d0n,
               nullptr, 0, last ? oh : nullptr);
    gbar(bcnt, 128, ++bar);
    u16* tp = d0c; d0c = d0n; d0n = tp;

    if (bx < 64)
      gru_dual(bx, d0c, nullptr, d1c, WdIH1, WdHH1, dbih1, dbhh1, cf, d1n,
               nullptr, 0, last ? (oh + BB * HH) : nullptr);
    gbar(bcnt, 128, ++bar);
    tp = d1c; d1c = d1n; d1n = tp;

    for (int vb = bx; vb < 1024; vb += 128)
      sim_body(vb, d1c, oe, simt);
    gbar(bcnt, 128, ++bar);

    smax_body(bx, simt, smax, ssum);
    gbar(bcnt, 128, ++bar);

    attn_body(bx, ts, simt, smax, ssum, d1c, oe, fcW, fcb, dout, tok);
    if (!last) gbar(bcnt, 128, ++bar);
  }
}

// Split a f32 matrix [rows][512] into [rows][hi x512 | lo x512] u16.
__global__ __launch_bounds__(256) void splitk(
    const float* __restrict__ src, u16* __restrict__ dst, int n)
{
  int i = blockIdx.x * 256 + threadIdx.x;
  if (i >= n) return;
  int r = i >> 9, k = i & 511;
  float v = src[i];
  u16 hi = f2b(v);
  dst[(size_t)r * 1024 + k]       = hi;
  dst[(size_t)r * 1024 + 512 + k] = f2b(v - b2f(hi));
}

__global__ __launch_bounds__(256) void initk(
    float* af, float* cf, u16* b0, u16* b1, u16* b2, u16* b3, int* tok,
    int* bars)
{
  int i = blockIdx.x * 256 + threadIdx.x;   // 131072 threads
  b0[i] = 0; b1[i] = 0; b2[i] = 0; b3[i] = 0;
  if (i < BB * HH) { af[i] = 0.f; cf[i] = 0.f; }
  if (i < BB) tok[i] = 0;
  if (i < 2) bars[i] = 0;
}

extern "C" void kernel_launch(void* const* d_in, const int* in_sizes, int n_in,
                              void* d_out, int out_size, void* d_ws, size_t ws_size,
                              hipStream_t stream) {
  const float* x     = (const float*)d_in[0];
  const float* emb   = (const float*)d_in[1];
  const float* eWih0 = (const float*)d_in[2];
  const float* eWhh0 = (const float*)d_in[3];
  const float* ebih0 = (const float*)d_in[4];
  const float* ebhh0 = (const float*)d_in[5];
  const float* eWih1 = (const float*)d_in[6];
  const float* eWhh1 = (const float*)d_in[7];
  const float* ebih1 = (const float*)d_in[8];
  const float* ebhh1 = (const float*)d_in[9];
  const float* dWih0 = (const float*)d_in[10];
  const float* dWhh0 = (const float*)d_in[11];
  const float* dbih0 = (const float*)d_in[12];
  const float* dbhh0 = (const float*)d_in[13];
  const float* dWih1 = (const float*)d_in[14];
  const float* dWhh1 = (const float*)d_in[15];
  const float* dbih1 = (const float*)d_in[16];
  const float* dbhh1 = (const float*)d_in[17];
  const float* fcW   = (const float*)d_in[18];
  const float* fcb   = (const float*)d_in[19];
  float* dout = (float*)d_out;

  char* wsb = (char*)d_ws;
  float* af   = (float*)(wsb + 0);          // 128x512 f32 (block-private RMW)
  float* cf   = (float*)(wsb + 262144);
  u16* ABF0   = (u16*)(wsb + 524288);       // split states 128x1024 u16 each
  u16* ABF1   = (u16*)(wsb + 786432);
  u16* CBF0   = (u16*)(wsb + 1048576);
  u16* CBF1   = (u16*)(wsb + 1310720);
  int* tok    = (int*)(wsb + 1572864);
  float* simt = (float*)(wsb + 1573376);    // [S][B] f32, 256 KB
  u16* WeHH0  = (u16*)(wsb + 1835520);      // split weights, 3 MB each
  u16* WeIH1  = (u16*)(wsb + 4981248);
  u16* WeHH1  = (u16*)(wsb + 8126976);
  u16* WdIH0  = (u16*)(wsb + 11272704);
  u16* WdHH0  = (u16*)(wsb + 14418432);
  u16* WdIH1  = (u16*)(wsb + 17564160);
  u16* WdHH1  = (u16*)(wsb + 20709888);
  u16* EMBs   = (u16*)(wsb + 23855616);     // 30x1024 u16
  u16* oe     = (u16*)(wsb + 23917056);     // out_enc bf16 [B][S][H], 64 MiB
  float* smax = (float*)(wsb + 91025920);   // [S] f32
  float* ssum = (float*)(wsb + 91028096);   // [S] f32
  int*   bars = (int*)  (wsb + 91032192);   // 2 barrier counters (workspace)

  initk<<<512, 256, 0, stream>>>(af, cf, ABF0, ABF1, CBF0, CBF1, tok, bars);

  const int WN = 3 * HH * HH;               // 786432
  splitk<<<(WN + 255) / 256, 256, 0, stream>>>(eWhh0, WeHH0, WN);
  splitk<<<(WN + 255) / 256, 256, 0, stream>>>(eWih1, WeIH1, WN);
  splitk<<<(WN + 255) / 256, 256, 0, stream>>>(eWhh1, WeHH1, WN);
  splitk<<<(WN + 255) / 256, 256, 0, stream>>>(dWih0, WdIH0, WN);
  splitk<<<(WN + 255) / 256, 256, 0, stream>>>(dWhh0, WdHH0, WN);
  splitk<<<(WN + 255) / 256, 256, 0, stream>>>(dWih1, WdIH1, WN);
  splitk<<<(WN + 255) / 256, 256, 0, stream>>>(dWhh1, WdHH1, WN);
  splitk<<<(VV * HH + 255) / 256, 256, 0, stream>>>(emb, EMBs, VV * HH);

  enc_persist<<<96, 256, 0, stream>>>(x, eWih0, WeHH0, ebih0, ebhh0,
                                      WeIH1, WeHH1, ebih1, ebhh1,
                                      ABF0, ABF1, af, CBF0, CBF1, cf,
                                      oe, bars);

  // phase parity (round-3 trace): a_511 split in ABF0, c_511 split in CBF1
  dec_persist<<<128, 256, 0, stream>>>(EMBs, ABF0, ABF1, CBF1, CBF0,
                                       WdIH0, WdHH0, dbih0, dbhh0,
                                       WdIH1, WdHH1, dbih1, dbhh1,
                                       af, cf, oe, fcW, fcb,
                                       simt, smax, ssum, dout, tok, bars + 1);
}